// Round 9
// baseline (53.329 us; speedup 1.0000x reference)
//
#include <hip/hip_runtime.h>
#include <math.h>

constexpr int NB = 256;   // batch
constexpr int NS = 128;   // seq len
constexpr int NE = 256;   // embed dim
constexpr int DIN = 260;  // E + H

constexpr float INV2PI = 0.15915494309189535f;

// ---------- fast primitives ----------
__device__ __forceinline__ float rcp_fast(float x) {
#if __has_builtin(__builtin_amdgcn_rcpf)
    return __builtin_amdgcn_rcpf(x);
#else
    return 1.0f / x;
#endif
}

// cos of (x revolutions): v_fract + v_cos, no libm reduction code.
__device__ __forceinline__ float cos_rev(float x) {
    float f, r;
    asm("v_fract_f32 %0, %1" : "=v"(f) : "v"(x));
    asm("v_cos_f32 %0, %1" : "=v"(r) : "v"(f));
    return r;
}

// DPP lane ops (all within 16-lane rows / 4-lane quads)
#define DPPF(x, CTRL) __int_as_float(__builtin_amdgcn_mov_dpp(__float_as_int(x), (CTRL), 0xF, 0xF, true))
#define DX1(x)   DPPF(x, 0xB1)   // quad_perm XOR1
#define DX2(x)   DPPF(x, 0x4E)   // quad_perm XOR2
#define DX3(x)   DPPF(x, 0x1B)   // quad_perm XOR3
#define DROR8(x) DPPF(x, 0x128)  // row_ror:8  == lane XOR 8 (within 16)
#define DHM(x)   DPPF(x, 0x141)  // row_half_mirror == lane XOR 7
#define DRM(x)   DPPF(x, 0x140)  // row_mirror == lane XOR 15

// Lambert continued-fraction tanh for the c-gate (|c| <= ~2.1): err ~2e-5.
__device__ __forceinline__ float tanh_cf(float y) {
    float w = y * y;
    float num = y * fmaf(fmaf(21.0f, w, 1260.0f), w, 10395.0f);
    float den = fmaf(fmaf(w + 210.0f, w, 4725.0f), w, 10395.0f);
    return num * rcp_fast(den);
}

__device__ __forceinline__ float sel4f(float v0, float v1, float v2, float v3,
                                       bool bit0, bool bit1) {
    float lo = bit0 ? v1 : v0;
    float hi = bit0 ? v3 : v2;
    return bit1 ? hi : lo;
}

// ---------------- Kernel 1: x-part of all 4 gate preactivations ----------------
// Output PRE-SCALED by 1/(2*pi). Tokens for all 16 rows loaded once (coalesced);
// 6-deep static gather ring of independent emb-row loads.
__global__ __launch_bounds__(256) void k_embed(
    const int* __restrict__ x, const float* __restrict__ emb,
    const float* __restrict__ Wf, const float* __restrict__ bf,
    const float* __restrict__ Wi, const float* __restrict__ bi,
    const float* __restrict__ Wu, const float* __restrict__ bu,
    const float* __restrict__ Wo, const float* __restrict__ bo,
    const float* __restrict__ thf, const float* __restrict__ thi,
    const float* __restrict__ thu, const float* __restrict__ tho,
    float* __restrict__ xpart)
{
    const int lane = threadIdx.x & 63;
    const int wave_id = blockIdx.x * 4 + (threadIdx.x >> 6);  // 0..2047
    const int row0 = wave_id * 16;

    const int tok16 = x[((row0 & 255) + (lane & 15)) * NS + (row0 >> 8)];

    float4 Wreg[16];
    #pragma unroll
    for (int j = 0; j < 16; ++j) {
        const float* Wgp = (j < 8) ? ((j < 4) ? Wf : Wi) : ((j < 12) ? Wu : Wo);
        float4 w = *(const float4*)(Wgp + (j & 3) * DIN + lane * 4);
        Wreg[j] = make_float4(w.x * INV2PI, w.y * INV2PI, w.z * INV2PI, w.w * INV2PI);
    }
    float biasv;
    {
        int j = lane & 15, jj = j & 3;
        const float* bp = (j < 8) ? ((j < 4) ? bf : bi) : ((j < 12) ? bu : bo);
        const float* tp = (j < 8) ? ((j < 4) ? thf : thi) : ((j < 12) ? thu : tho);
        biasv = (bp[jj] + tp[jj]) * INV2PI;
    }

    const bool p0 = (lane & 1) != 0, p1 = (lane & 2) != 0,
               p2 = (lane & 4) != 0, p3 = (lane & 8) != 0;

#define LDE(I) (*(const float4*)(emb + \
    (size_t)(unsigned)__shfl(tok16, (I), 64) * NE + lane * 4))

#define PROC(I, EV) do {                                                     \
    float acc[16];                                                           \
    _Pragma("unroll")                                                        \
    for (int j = 0; j < 16; ++j) {                                           \
        float4 wv = Wreg[j];                                                 \
        acc[j] = fmaf((EV).x, wv.x, fmaf((EV).y, wv.y,                       \
                  fmaf((EV).z, wv.z, (EV).w * wv.w)));                       \
    }                                                                        \
    float t8[8];                                                             \
    _Pragma("unroll")                                                        \
    for (int i2 = 0; i2 < 8; ++i2) {                                         \
        float keep = p0 ? acc[2 * i2 + 1] : acc[2 * i2];                     \
        float send = p0 ? acc[2 * i2] : acc[2 * i2 + 1];                     \
        t8[i2] = keep + __shfl_xor(send, 1, 64);                             \
    }                                                                        \
    float t4[4];                                                             \
    _Pragma("unroll")                                                        \
    for (int i2 = 0; i2 < 4; ++i2) {                                         \
        float keep = p1 ? t8[2 * i2 + 1] : t8[2 * i2];                       \
        float send = p1 ? t8[2 * i2] : t8[2 * i2 + 1];                       \
        t4[i2] = keep + __shfl_xor(send, 2, 64);                             \
    }                                                                        \
    float t2[2];                                                             \
    _Pragma("unroll")                                                        \
    for (int i2 = 0; i2 < 2; ++i2) {                                         \
        float keep = p2 ? t4[2 * i2 + 1] : t4[2 * i2];                       \
        float send = p2 ? t4[2 * i2] : t4[2 * i2 + 1];                       \
        t2[i2] = keep + __shfl_xor(send, 4, 64);                             \
    }                                                                        \
    float keep = p3 ? t2[1] : t2[0];                                         \
    float send = p3 ? t2[0] : t2[1];                                         \
    float t1 = keep + __shfl_xor(send, 8, 64);                               \
    t1 += __shfl_xor(t1, 16, 64);                                            \
    t1 += __shfl_xor(t1, 32, 64);                                            \
    if (lane < 16)                                                           \
        xpart[(size_t)(row0 + (I)) * 16 + lane] = t1 + biasv;                \
} while (0)

    float4 ev0 = LDE(0), ev1 = LDE(1), ev2 = LDE(2),
           ev3 = LDE(3), ev4 = LDE(4), ev5 = LDE(5);
    PROC(0,  ev0); ev0 = LDE(6);
    PROC(1,  ev1); ev1 = LDE(7);
    PROC(2,  ev2); ev2 = LDE(8);
    PROC(3,  ev3); ev3 = LDE(9);
    PROC(4,  ev4); ev4 = LDE(10);
    PROC(5,  ev5); ev5 = LDE(11);
    PROC(6,  ev0); ev0 = LDE(12);
    PROC(7,  ev1); ev1 = LDE(13);
    PROC(8,  ev2); ev2 = LDE(14);
    PROC(9,  ev3); ev3 = LDE(15);
    PROC(10, ev4);
    PROC(11, ev5);
    PROC(12, ev0);
    PROC(13, ev1);
    PROC(14, ev2);
    PROC(15, ev3);
#undef PROC
#undef LDE
}

// ---------------- Kernel 2: recurrence, 16 lanes/batch + fused logits ----------------
// lane = 16*grp + 4*g + j : batch-in-wave grp (4/wave), gate g, index j.
// Each lane: 1 preactivation fma-tree, 1 cos, 1 gate-poly. cos-products via
// in-quad DPP multiply scan; gate exchange via ror8/mirror DPP. 64 blocks x 64.
__global__ __launch_bounds__(64) void k_recur(
    const float* __restrict__ Wf, const float* __restrict__ Wi,
    const float* __restrict__ Wu, const float* __restrict__ Wo,
    const float* __restrict__ xpart,
    const float* __restrict__ Wc, const float* __restrict__ bc,
    float* __restrict__ out)
{
    __shared__ float hlds[128][16];   // 8 KB: [s][grp*4+j]

    const int lane = threadIdx.x;
    const int grp = lane >> 4;
    const int q   = lane & 15;
    const int g   = q >> 2;
    const int j   = q & 3;
    const int b0  = blockIdx.x * 4;

    // pre-permuted recurrent weights (revolutions): W'[k] = Wg[j][256+(j^k)]/2pi
    const float* Wg = (g == 0) ? Wf : ((g == 1) ? Wi : ((g == 2) ? Wu : Wo));
    const float W0 = Wg[j * DIN + 256 + (j ^ 0)] * INV2PI;
    const float W1 = Wg[j * DIN + 256 + (j ^ 1)] * INV2PI;
    const float W2 = Wg[j * DIN + 256 + (j ^ 2)] * INV2PI;
    const float W3 = Wg[j * DIN + 256 + (j ^ 3)] * INV2PI;

    const bool j0 = (j & 1) != 0, j1 = (j & 2) != 0;
    const bool g0 = (g & 1) != 0, g1 = (g & 2) != 0;
    const bool isj1 = (j == 1);

    // act(q) = bas + mlt*tanh(scl*q), poly coeffs with mlt*scl^(2k+1) folded in
    const float scl = (g == 2) ? 1.0f : 0.5f;
    const float mlt = (g == 2) ? 1.0f : 0.5f;
    const float bas = (g == 2) ? 0.0f : 0.5f;
    const float s2 = scl * scl;
    const float D0s = mlt * 0.999416f * scl;
    const float D1s = mlt * -0.326958f * scl * s2;
    const float D2s = mlt * 0.111796f * scl * s2 * s2;
    const float D3s = mlt * -0.022660f * scl * s2 * s2 * s2;

    float c = 0.0f;
    float hr0 = 0.f, hr1 = 0.f, hr2 = 0.f, hr3 = 0.f;  // hr[k] = h[j^k]

    // per-lane feed: element (s, b0+grp, q) = xpart[s*4096 + b0*16 + lane]
    const float* xblk = xpart + b0 * 16 + lane;

#define LDXs(CH, K) (xblk[(size_t)(((CH) * 16 + (K)) * 4096)])

#define QS(XC, S) do {                                                        \
    float t_ = fmaf(W0, hr0, (XC));                                           \
    float u_ = W1 * hr1;                                                      \
    t_ = fmaf(W2, hr2, t_);                                                   \
    u_ = fmaf(W3, hr3, u_);                                                   \
    float a_ = t_ + u_;                                                       \
    float cv = cos_rev(a_);                                                   \
    float d1 = DX1(cv);                                                       \
    float t1 = cv * d1;                                                       \
    float d2 = DX2(t1);                                                       \
    float X_ = sel4f(d1, t1, cv, t1, j0, j1);                                 \
    float Y_ = isj1 ? 1.0f : d2;                                              \
    float P_ = X_ * Y_;                                                       \
    float w_ = P_ * P_;                                                       \
    float p_ = fmaf(fmaf(fmaf(D3s, w_, D2s), w_, D1s), w_, D0s);              \
    float A_ = fmaf(P_, p_, bas);                                             \
    float t3 = DX3(A_);                                                       \
    float A4 = DHM(t3);    /* A[lane^4]  = gate g^1 */                        \
    float A8 = DROR8(A_);  /* A[lane^8]  = gate g^2 */                        \
    float A12 = DRM(t3);   /* A[lane^12] = gate g^3 */                        \
    float fv = sel4f(A_,  A4,  A8,  A12, g0, g1);                             \
    float iv = sel4f(A4,  A_,  A12, A8,  g0, g1);                             \
    float uv = sel4f(A8,  A12, A_,  A4,  g0, g1);                             \
    float ov = sel4f(A12, A8,  A4,  A_,  g0, g1);                             \
    c = fmaf(fv, c, iv * uv);                                                 \
    float hn = ov * tanh_cf(c);                                               \
    hlds[S][(grp << 2) | j] = hn;                                             \
    hr0 = hn;                                                                 \
    hr1 = DX1(hn);                                                            \
    hr2 = DX2(hn);                                                            \
    hr3 = DX3(hn);                                                            \
} while (0)

    // preload chunks 0 and 1 (32 scalar loads, 16 steps each)
    float xA0 = LDXs(0, 0),  xA1 = LDXs(0, 1),  xA2 = LDXs(0, 2),  xA3 = LDXs(0, 3);
    float xA4 = LDXs(0, 4),  xA5 = LDXs(0, 5),  xA6 = LDXs(0, 6),  xA7 = LDXs(0, 7);
    float xA8 = LDXs(0, 8),  xA9 = LDXs(0, 9),  xA10 = LDXs(0, 10), xA11 = LDXs(0, 11);
    float xA12 = LDXs(0, 12), xA13 = LDXs(0, 13), xA14 = LDXs(0, 14), xA15 = LDXs(0, 15);
    float xB0 = LDXs(1, 0),  xB1 = LDXs(1, 1),  xB2 = LDXs(1, 2),  xB3 = LDXs(1, 3);
    float xB4 = LDXs(1, 4),  xB5 = LDXs(1, 5),  xB6 = LDXs(1, 6),  xB7 = LDXs(1, 7);
    float xB8 = LDXs(1, 8),  xB9 = LDXs(1, 9),  xB10 = LDXs(1, 10), xB11 = LDXs(1, 11);
    float xB12 = LDXs(1, 12), xB13 = LDXs(1, 13), xB14 = LDXs(1, 14), xB15 = LDXs(1, 15);

    for (int cp = 0; cp < 3; ++cp) {
        int s0 = cp * 32;
        int chA = cp * 2 + 2;
        int chB = cp * 2 + 3;
        QS(xA0, s0 + 0);   xA0 = LDXs(chA, 0);
        QS(xA1, s0 + 1);   xA1 = LDXs(chA, 1);
        QS(xA2, s0 + 2);   xA2 = LDXs(chA, 2);
        QS(xA3, s0 + 3);   xA3 = LDXs(chA, 3);
        QS(xA4, s0 + 4);   xA4 = LDXs(chA, 4);
        QS(xA5, s0 + 5);   xA5 = LDXs(chA, 5);
        QS(xA6, s0 + 6);   xA6 = LDXs(chA, 6);
        QS(xA7, s0 + 7);   xA7 = LDXs(chA, 7);
        QS(xA8, s0 + 8);   xA8 = LDXs(chA, 8);
        QS(xA9, s0 + 9);   xA9 = LDXs(chA, 9);
        QS(xA10, s0 + 10); xA10 = LDXs(chA, 10);
        QS(xA11, s0 + 11); xA11 = LDXs(chA, 11);
        QS(xA12, s0 + 12); xA12 = LDXs(chA, 12);
        QS(xA13, s0 + 13); xA13 = LDXs(chA, 13);
        QS(xA14, s0 + 14); xA14 = LDXs(chA, 14);
        QS(xA15, s0 + 15); xA15 = LDXs(chA, 15);
        QS(xB0, s0 + 16);  xB0 = LDXs(chB, 0);
        QS(xB1, s0 + 17);  xB1 = LDXs(chB, 1);
        QS(xB2, s0 + 18);  xB2 = LDXs(chB, 2);
        QS(xB3, s0 + 19);  xB3 = LDXs(chB, 3);
        QS(xB4, s0 + 20);  xB4 = LDXs(chB, 4);
        QS(xB5, s0 + 21);  xB5 = LDXs(chB, 5);
        QS(xB6, s0 + 22);  xB6 = LDXs(chB, 6);
        QS(xB7, s0 + 23);  xB7 = LDXs(chB, 7);
        QS(xB8, s0 + 24);  xB8 = LDXs(chB, 8);
        QS(xB9, s0 + 25);  xB9 = LDXs(chB, 9);
        QS(xB10, s0 + 26); xB10 = LDXs(chB, 10);
        QS(xB11, s0 + 27); xB11 = LDXs(chB, 11);
        QS(xB12, s0 + 28); xB12 = LDXs(chB, 12);
        QS(xB13, s0 + 29); xB13 = LDXs(chB, 13);
        QS(xB14, s0 + 30); xB14 = LDXs(chB, 14);
        QS(xB15, s0 + 31); xB15 = LDXs(chB, 15);
    }
    // final 32 steps: no prefetch
    QS(xA0, 96);  QS(xA1, 97);  QS(xA2, 98);  QS(xA3, 99);
    QS(xA4, 100); QS(xA5, 101); QS(xA6, 102); QS(xA7, 103);
    QS(xA8, 104); QS(xA9, 105); QS(xA10, 106); QS(xA11, 107);
    QS(xA12, 108); QS(xA13, 109); QS(xA14, 110); QS(xA15, 111);
    QS(xB0, 112); QS(xB1, 113); QS(xB2, 114); QS(xB3, 115);
    QS(xB4, 116); QS(xB5, 117); QS(xB6, 118); QS(xB7, 119);
    QS(xB8, 120); QS(xB9, 121); QS(xB10, 122); QS(xB11, 123);
    QS(xB12, 124); QS(xB13, 125); QS(xB14, 126); QS(xB15, 127);
#undef QS
#undef LDXs

    // ---------- fused logits + log_softmax epilogue (same math as old k_out) ----
    asm volatile("s_waitcnt lgkmcnt(0)" ::: "memory");
    const int t0 = (lane & 7) * 4;
    float4 w0 = *(const float4*)(Wc + (t0 + 0) * 4);
    float4 w1 = *(const float4*)(Wc + (t0 + 1) * 4);
    float4 w2 = *(const float4*)(Wc + (t0 + 2) * 4);
    float4 w3 = *(const float4*)(Wc + (t0 + 3) * 4);
    float4 bv = *(const float4*)(bc + t0);

    for (int pass = 0; pass < 64; ++pass) {
        int r = pass * 8 + (lane >> 3);   // 0..511 = bat*128 + s
        int bat = r >> 7, s = r & 127;
        float4 h4 = *(const float4*)&hlds[s][bat * 4];
        float l0 = bv.x + w0.x * h4.x + w0.y * h4.y + w0.z * h4.z + w0.w * h4.w;
        float l1 = bv.y + w1.x * h4.x + w1.y * h4.y + w1.z * h4.z + w1.w * h4.w;
        float l2 = bv.z + w2.x * h4.x + w2.y * h4.y + w2.z * h4.z + w2.w * h4.w;
        float l3 = bv.w + w3.x * h4.x + w3.y * h4.y + w3.z * h4.z + w3.w * h4.w;
        float m = fmaxf(fmaxf(l0, l1), fmaxf(l2, l3));
        m = fmaxf(m, __shfl_xor(m, 1, 64));
        m = fmaxf(m, __shfl_xor(m, 2, 64));
        m = fmaxf(m, __shfl_xor(m, 4, 64));
        float sum = __expf(l0 - m) + __expf(l1 - m) + __expf(l2 - m) + __expf(l3 - m);
        sum += __shfl_xor(sum, 1, 64);
        sum += __shfl_xor(sum, 2, 64);
        sum += __shfl_xor(sum, 4, 64);
        float base = m + __logf(sum);
        float4 o;
        o.x = l0 - base; o.y = l1 - base; o.z = l2 - base; o.w = l3 - base;
        *(float4*)(out + ((size_t)(b0 + bat) * 128 + s) * 32 + t0) = o;
    }
}

extern "C" void kernel_launch(void* const* d_in, const int* in_sizes, int n_in,
                              void* d_out, int out_size, void* d_ws, size_t ws_size,
                              hipStream_t stream) {
    const int*   x   = (const int*)d_in[0];
    const float* emb = (const float*)d_in[1];
    const float* Wf  = (const float*)d_in[2];
    const float* bf  = (const float*)d_in[3];
    const float* Wi  = (const float*)d_in[4];
    const float* bi  = (const float*)d_in[5];
    const float* Wu  = (const float*)d_in[6];
    const float* bu  = (const float*)d_in[7];
    const float* Wo  = (const float*)d_in[8];
    const float* bo  = (const float*)d_in[9];
    const float* thf = (const float*)d_in[10];
    const float* thi = (const float*)d_in[11];
    const float* thu = (const float*)d_in[12];
    const float* tho = (const float*)d_in[13];
    const float* Wc  = (const float*)d_in[14];
    const float* bc  = (const float*)d_in[15];
    float* out = (float*)d_out;

    float* xpart = (float*)d_ws;                    // [S][B][16]  2 MB

    k_embed<<<512, 256, 0, stream>>>(x, emb, Wf, bf, Wi, bi, Wu, bu, Wo, bo,
                                     thf, thi, thu, tho, xpart);
    k_recur<<<64, 64, 0, stream>>>(Wf, Wi, Wu, Wo, xpart, Wc, bc, out);
}